// Round 7
// baseline (57.140 us; speedup 1.0000x reference)
//
#include <hip/hip_runtime.h>

// Complex BatchNorm (training whitening), z:[B=32, N=C*H*W, 2] fp32.
// float4 (2 positions) per thread x 16 batch samples (2-way batch split
// across lane halves). 16 float4 loads pinned in registers, 10 shuffle
// reduces (xor 32), redundant 2x2 matrix per half, 16 nt float4 stores.
// Halves VMEM instruction count vs the float2 single-pass variant while
// keeping 512B-contiguous per-half-wave segments.

constexpr int BATCH = 32;
constexpr int BHALF = BATCH / 2;   // 16 samples per thread

typedef float f32x4 __attribute__((ext_vector_type(4)));

__global__ __launch_bounds__(256) void cbn_kernel(
    const float4* __restrict__ z,
    const float* __restrict__ gamma,
    const float* __restrict__ beta,
    float4* __restrict__ out,
    int N2)   // N2 = N/2 float4 "pair" positions
{
    const int lane  = threadIdx.x & 63;
    const int gwave = (blockIdx.x * blockDim.x + threadIdx.x) >> 6;
    const int col   = gwave * 32 + (lane & 31);  // float4 column (2 positions)
    if (col >= N2) return;
    const int h = lane >> 5;                     // batch half: 0 or 1

    // ---- load my 16 batch samples (64 data VGPRs) ----
    float4 v[BHALF];
#pragma unroll
    for (int k = 0; k < BHALF; ++k) {
        v[k] = z[(size_t)(h * BHALF + k) * N2 + col];
    }
    // Pin: forbid rematerialization/reload of the samples.
#pragma unroll
    for (int k = 0; k < BHALF; ++k) {
        asm volatile("" : "+v"(v[k].x), "+v"(v[k].y), "+v"(v[k].z), "+v"(v[k].w));
    }

    // ---- partial raw moments over my 16 samples (both positions) ----
    float sx0 = 0.f, sy0 = 0.f, sxx0 = 0.f, sxy0 = 0.f, syy0 = 0.f;
    float sx1 = 0.f, sy1 = 0.f, sxx1 = 0.f, sxy1 = 0.f, syy1 = 0.f;
#pragma unroll
    for (int k = 0; k < BHALF; ++k) {
        float4 q = v[k];
        sx0 += q.x; sy0 += q.y;
        sxx0 = fmaf(q.x, q.x, sxx0);
        sxy0 = fmaf(q.x, q.y, sxy0);
        syy0 = fmaf(q.y, q.y, syy0);
        sx1 += q.z; sy1 += q.w;
        sxx1 = fmaf(q.z, q.z, sxx1);
        sxy1 = fmaf(q.z, q.w, sxy1);
        syy1 = fmaf(q.w, q.w, syy1);
    }

    // ---- complete sums across the two batch halves ----
#define RED(a) a += __shfl_xor(a, 32);
    RED(sx0) RED(sy0) RED(sxx0) RED(sxy0) RED(syy0)
    RED(sx1) RED(sy1) RED(sxx1) RED(sxy1) RED(syy1)
#undef RED

    const float invB  = 1.0f / BATCH;
    const float invB1 = 1.0f / (BATCH - 1);

    const float g00 = gamma[0], g01 = gamma[1], g10 = gamma[2], g11 = gamma[3];
    const float be0 = beta[0], be1 = beta[1];

    // ---- 2x2 whitening matrix (gamma-fused), position 0 ----
    float mx0 = sx0 * invB, my0 = sy0 * invB;
    float cxx0 = (sxx0 - BATCH * mx0 * mx0) * invB1;
    float cxy0 = (sxy0 - BATCH * mx0 * my0) * invB1;
    float cyy0 = (syy0 - BATCH * my0 * my0) * invB1;
    float s0  = sqrtf(cxx0 * cyy0 - cxy0 * cxy0);
    float rt0 = 1.0f / sqrtf(cxx0 + cyy0 + 2.0f * s0);
    float a00_0 = (cxx0 + s0) * rt0, a01_0 = cxy0 * rt0, a11_0 = (cyy0 + s0) * rt0;
    float c00_0 = g00 * a00_0 + g01 * a01_0;
    float c01_0 = g00 * a01_0 + g01 * a11_0;
    float c10_0 = g10 * a00_0 + g11 * a01_0;
    float c11_0 = g10 * a01_0 + g11 * a11_0;

    // ---- position 1 ----
    float mx1 = sx1 * invB, my1 = sy1 * invB;
    float cxx1 = (sxx1 - BATCH * mx1 * mx1) * invB1;
    float cxy1 = (sxy1 - BATCH * mx1 * my1) * invB1;
    float cyy1 = (syy1 - BATCH * my1 * my1) * invB1;
    float s1  = sqrtf(cxx1 * cyy1 - cxy1 * cxy1);
    float rt1 = 1.0f / sqrtf(cxx1 + cyy1 + 2.0f * s1);
    float a00_1 = (cxx1 + s1) * rt1, a01_1 = cxy1 * rt1, a11_1 = (cyy1 + s1) * rt1;
    float c00_1 = g00 * a00_1 + g01 * a01_1;
    float c01_1 = g00 * a01_1 + g01 * a11_1;
    float c10_1 = g10 * a00_1 + g11 * a01_1;
    float c11_1 = g10 * a01_1 + g11 * a11_1;

    // ---- apply to my 16 retained samples, nontemporal float4 stores ----
#pragma unroll
    for (int k = 0; k < BHALF; ++k) {
        float4 q = v[k];
        float dx0 = q.x - mx0, dy0 = q.y - my0;
        float dx1 = q.z - mx1, dy1 = q.w - my1;
        f32x4 o;
        o.x = fmaf(c00_0, dx0, fmaf(c01_0, dy0, be0));
        o.y = fmaf(c10_0, dx0, fmaf(c11_0, dy0, be1));
        o.z = fmaf(c00_1, dx1, fmaf(c01_1, dy1, be0));
        o.w = fmaf(c10_1, dx1, fmaf(c11_1, dy1, be1));
        __builtin_nontemporal_store(o,
            (f32x4*)&out[(size_t)(h * BHALF + k) * N2 + col]);
    }
}

extern "C" void kernel_launch(void* const* d_in, const int* in_sizes, int n_in,
                              void* d_out, int out_size, void* d_ws, size_t ws_size,
                              hipStream_t stream) {
    const float4* z    = (const float4*)d_in[0];
    const float* gamma = (const float*)d_in[1];
    const float* beta  = (const float*)d_in[2];
    float4* out = (float4*)d_out;

    // in_sizes[0] = B * N * 2; float4 "pair" positions: N2 = N/2
    int N2 = in_sizes[0] / (BATCH * 4);

    // 2 threads per float4 column (batch halves), 32 columns per wave.
    long long total_threads = (long long)N2 * 2;
    dim3 block(256);
    dim3 grid((unsigned)((total_threads + block.x - 1) / block.x));
    hipLaunchKernelGGL(cbn_kernel, grid, block, 0, stream, z, gamma, beta, out, N2);
}

// Round 8
// 55.799 us; speedup vs baseline: 1.0240x; 1.0240x over previous
//
#include <hip/hip_runtime.h>

// Complex BatchNorm (training whitening), z:[B=32, N=C*H*W, 2] fp32.
// One thread = one float4 column (2 positions), all 32 batch samples
// loaded as float4 and PINNED in registers (128 data VGPRs). No lane
// split, no shuffles: every global access is a single contiguous 1KB
// wave segment (64 lanes x 16B) -- max DRAM burst per stream.

constexpr int BATCH = 32;

typedef float f32x4 __attribute__((ext_vector_type(4)));

__global__ __launch_bounds__(256) void cbn_kernel(
    const float4* __restrict__ z,
    const float* __restrict__ gamma,
    const float* __restrict__ beta,
    float4* __restrict__ out,
    int N2)   // N2 = N/2 float4 "pair" positions
{
    int col = blockIdx.x * blockDim.x + threadIdx.x;
    if (col >= N2) return;

    // ---- load all 32 batch samples (128 data VGPRs) ----
    float4 v[BATCH];
#pragma unroll
    for (int b = 0; b < BATCH; ++b) {
        v[b] = z[(size_t)b * N2 + col];
    }
    // Pin: forbid rematerialization/reload of the samples.
#pragma unroll
    for (int b = 0; b < BATCH; ++b) {
        asm volatile("" : "+v"(v[b].x), "+v"(v[b].y), "+v"(v[b].z), "+v"(v[b].w));
    }

    // ---- raw moments for both positions ----
    float sx0 = 0.f, sy0 = 0.f, sxx0 = 0.f, sxy0 = 0.f, syy0 = 0.f;
    float sx1 = 0.f, sy1 = 0.f, sxx1 = 0.f, sxy1 = 0.f, syy1 = 0.f;
#pragma unroll
    for (int b = 0; b < BATCH; ++b) {
        float4 q = v[b];
        sx0 += q.x; sy0 += q.y;
        sxx0 = fmaf(q.x, q.x, sxx0);
        sxy0 = fmaf(q.x, q.y, sxy0);
        syy0 = fmaf(q.y, q.y, syy0);
        sx1 += q.z; sy1 += q.w;
        sxx1 = fmaf(q.z, q.z, sxx1);
        sxy1 = fmaf(q.z, q.w, sxy1);
        syy1 = fmaf(q.w, q.w, syy1);
    }

    const float invB  = 1.0f / BATCH;
    const float invB1 = 1.0f / (BATCH - 1);

    const float g00 = gamma[0], g01 = gamma[1], g10 = gamma[2], g11 = gamma[3];
    const float be0 = beta[0], be1 = beta[1];

    // ---- 2x2 whitening matrix (gamma-fused), position 0 ----
    float mx0 = sx0 * invB, my0 = sy0 * invB;
    float cxx0 = (sxx0 - BATCH * mx0 * mx0) * invB1;
    float cxy0 = (sxy0 - BATCH * mx0 * my0) * invB1;
    float cyy0 = (syy0 - BATCH * my0 * my0) * invB1;
    float s0  = sqrtf(cxx0 * cyy0 - cxy0 * cxy0);
    float rt0 = 1.0f / sqrtf(cxx0 + cyy0 + 2.0f * s0);
    float a00_0 = (cxx0 + s0) * rt0, a01_0 = cxy0 * rt0, a11_0 = (cyy0 + s0) * rt0;
    float c00_0 = g00 * a00_0 + g01 * a01_0;
    float c01_0 = g00 * a01_0 + g01 * a11_0;
    float c10_0 = g10 * a00_0 + g11 * a01_0;
    float c11_0 = g10 * a01_0 + g11 * a11_0;

    // ---- position 1 ----
    float mx1 = sx1 * invB, my1 = sy1 * invB;
    float cxx1 = (sxx1 - BATCH * mx1 * mx1) * invB1;
    float cxy1 = (sxy1 - BATCH * mx1 * my1) * invB1;
    float cyy1 = (syy1 - BATCH * my1 * my1) * invB1;
    float s1  = sqrtf(cxx1 * cyy1 - cxy1 * cxy1);
    float rt1 = 1.0f / sqrtf(cxx1 + cyy1 + 2.0f * s1);
    float a00_1 = (cxx1 + s1) * rt1, a01_1 = cxy1 * rt1, a11_1 = (cyy1 + s1) * rt1;
    float c00_1 = g00 * a00_1 + g01 * a01_1;
    float c01_1 = g00 * a01_1 + g01 * a11_1;
    float c10_1 = g10 * a00_1 + g11 * a01_1;
    float c11_1 = g10 * a01_1 + g11 * a11_1;

    // ---- apply to the 32 retained samples, nontemporal float4 stores ----
#pragma unroll
    for (int b = 0; b < BATCH; ++b) {
        float4 q = v[b];
        float dx0 = q.x - mx0, dy0 = q.y - my0;
        float dx1 = q.z - mx1, dy1 = q.w - my1;
        f32x4 o;
        o.x = fmaf(c00_0, dx0, fmaf(c01_0, dy0, be0));
        o.y = fmaf(c10_0, dx0, fmaf(c11_0, dy0, be1));
        o.z = fmaf(c00_1, dx1, fmaf(c01_1, dy1, be0));
        o.w = fmaf(c10_1, dx1, fmaf(c11_1, dy1, be1));
        __builtin_nontemporal_store(o, (f32x4*)&out[(size_t)b * N2 + col]);
    }
}

extern "C" void kernel_launch(void* const* d_in, const int* in_sizes, int n_in,
                              void* d_out, int out_size, void* d_ws, size_t ws_size,
                              hipStream_t stream) {
    const float4* z    = (const float4*)d_in[0];
    const float* gamma = (const float*)d_in[1];
    const float* beta  = (const float*)d_in[2];
    float4* out = (float4*)d_out;

    // in_sizes[0] = B * N * 2; float4 "pair" positions: N2 = N/2
    int N2 = in_sizes[0] / (BATCH * 4);

    dim3 block(256);
    dim3 grid((N2 + block.x - 1) / block.x);
    hipLaunchKernelGGL(cbn_kernel, grid, block, 0, stream, z, gamma, beta, out, N2);
}